// Round 7
// baseline (370.285 us; speedup 1.0000x reference)
//
#include <hip/hip_runtime.h>

// BottleneckAttention: LN -> QKV(+bias) -> RoPE(q,k) -> softmax(QK^T/8)V -> O-proj + residual
// B=2 N=2048 D=1024 H=16 hd=64. bf16 MFMA 16x16x32, fp32 accum.
// Layouts (learn_hip m89/m91): C/D: col=lane&15, row=(lane>>4)*4+reg
//                              A/B: m(or n)=lane&15, k=(lane>>4)*8+j
// v7: LDS-FREE fragments. Every A/B fragment is a contiguous 16B row-segment
// -> load it directly from global (L1/L2 serve the reuse; each 128B line is
// one row's K-tile so same-line lanes coalesce). No barriers in any K-loop;
// compiler pipelines loads across MFMAs. Only LDS left: attention's per-wave
// P (C->A layout) round-trip, stride-64 + 16B XOR swizzle (conflict-free).

#define SEQ 2048
#define LN_EPS 1e-5f

using short8 = __attribute__((ext_vector_type(8))) short;
using f32x4  = __attribute__((ext_vector_type(4))) float;

__device__ __forceinline__ unsigned short f2bf(float f) {
  union { float f; unsigned u; } v; v.f = f;
  unsigned r = v.u + 0x7FFFu + ((v.u >> 16) & 1u);  // RNE
  return (unsigned short)(r >> 16);
}

// ---------------- fused prep: weight fp32->bf16 | layernorm | rope table ----------------
__global__ __launch_bounds__(256) void prep_kernel(
    const float* __restrict__ x, const float* __restrict__ lnw, const float* __restrict__ lnb,
    const float* __restrict__ wq, const float* __restrict__ wk,
    const float* __restrict__ wv, const float* __restrict__ wo,
    unsigned short* __restrict__ wqkv, unsigned short* __restrict__ wob,
    unsigned short* __restrict__ xn, float2* __restrict__ tab) {
  const int b = blockIdx.x, t = threadIdx.x;
  if (b < 4096) {
    // ---- weight convert: 1M float4 units over 4 matrices ----
    const int gid = b * 256 + t;
    const int m = gid >> 18, e4 = gid & 262143;
    const float* src = (m == 0) ? wq : (m == 1) ? wk : (m == 2) ? wv : wo;
    const float4 v = ((const float4*)src)[e4];
    ushort4 o; o.x = f2bf(v.x); o.y = f2bf(v.y); o.z = f2bf(v.z); o.w = f2bf(v.w);
    if (m < 3) ((ushort4*)wqkv)[(size_t)m * 262144 + e4] = o;
    else       ((ushort4*)wob)[e4] = o;
  } else if (b < 8192) {
    // ---- layernorm row ----
    const int row = b - 4096;
    const float4 v = ((const float4*)(x + (size_t)row * 1024))[t];
    float s  = v.x + v.y + v.z + v.w;
    float s2 = v.x * v.x + v.y * v.y + v.z * v.z + v.w * v.w;
#pragma unroll
    for (int off = 32; off >= 1; off >>= 1) {
      s  += __shfl_xor(s, off);
      s2 += __shfl_xor(s2, off);
    }
    __shared__ float red[8];
    const int lane = t & 63, wave = t >> 6;
    if (lane == 0) { red[wave] = s; red[4 + wave] = s2; }
    __syncthreads();
    s  = red[0] + red[1] + red[2] + red[3];
    s2 = red[4] + red[5] + red[6] + red[7];
    const float mu   = s * (1.0f / 1024.0f);
    const float var  = s2 * (1.0f / 1024.0f) - mu * mu;
    const float rstd = rsqrtf(var + LN_EPS);
    const float4 wv4 = ((const float4*)lnw)[t];
    const float4 bv4 = ((const float4*)lnb)[t];
    ushort4 o;
    o.x = f2bf((v.x - mu) * rstd * wv4.x + bv4.x);
    o.y = f2bf((v.y - mu) * rstd * wv4.y + bv4.y);
    o.z = f2bf((v.z - mu) * rstd * wv4.z + bv4.z);
    o.w = f2bf((v.w - mu) * rstd * wv4.w + bv4.w);
    ((ushort4*)xn)[(size_t)row * 256 + t] = o;
  } else {
    // ---- rope table: tab[pos][i] = (cos, sin), 65536 entries ----
    const int gid = (b - 8192) * 256 + t;
    const int pos = gid >> 5, ip = gid & 31;
    const float invf = exp2f((float)ip * -0.4152410118609203f);  // 10000^(-2i/64)
    const float fr = (float)pos * invf;
    tab[gid] = make_float2(cosf(fr), sinf(fr));
  }
}

// ---------------- QKV GEMM 128x128, LDS-free, fused bias+RoPE ----------------
__global__ __launch_bounds__(256, 3) void gemm_qkv_kernel(
    const unsigned short* __restrict__ A,   // 4096 x 1024 bf16 (xn)
    const unsigned short* __restrict__ Bw,  // 3072 x 1024 bf16 (Wq;Wk;Wv rows)
    const float* __restrict__ bq, const float* __restrict__ bk, const float* __restrict__ bv,
    const float2* __restrict__ tab,
    unsigned short* __restrict__ qb, unsigned short* __restrict__ kbg,
    unsigned short* __restrict__ vtb) {
  const int tid = threadIdx.x;
  const int lane = tid & 63, wave = tid >> 6;
  const int lr = lane & 15, quad = lane >> 4;
  const int wm = (wave >> 1) * 64, wn = (wave & 1) * 64;
  const int n0 = blockIdx.x * 128, m0 = blockIdx.y * 128;

  const unsigned short* ap[4];
  const unsigned short* bp[4];
#pragma unroll
  for (int i = 0; i < 4; ++i) {
    ap[i] = &A[(size_t)(m0 + wm + i * 16 + lr) * 1024 + quad * 8];
    bp[i] = &Bw[(size_t)(n0 + wn + i * 16 + lr) * 1024 + quad * 8];
  }

  f32x4 acc[4][4];
#pragma unroll
  for (int i = 0; i < 4; ++i)
#pragma unroll
    for (int j = 0; j < 4; ++j) acc[i][j] = (f32x4){0.f, 0.f, 0.f, 0.f};

  for (int kt = 0; kt < 16; ++kt) {
#pragma unroll
    for (int kk = 0; kk < 2; ++kk) {
      const int off = kt * 64 + kk * 32;
      short8 a[4], b[4];
#pragma unroll
      for (int i = 0; i < 4; ++i) a[i] = *(const short8*)(ap[i] + off);
#pragma unroll
      for (int j = 0; j < 4; ++j) b[j] = *(const short8*)(bp[j] + off);
#pragma unroll
      for (int i = 0; i < 4; ++i)
#pragma unroll
        for (int j = 0; j < 4; ++j)
          acc[i][j] = __builtin_amdgcn_mfma_f32_16x16x32_bf16(a[i], b[j], acc[i][j], 0, 0, 0);
    }
  }

  const int which = n0 >> 10;  // block-uniform: 0=q 1=k 2=v
  const float* bias = (which == 0) ? bq : (which == 1) ? bk : bv;
  const float qs = (which == 0) ? 0.18033688011112042f : 1.0f;  // 0.125*log2(e)
#pragma unroll
  for (int i = 0; i < 4; ++i)
#pragma unroll
    for (int j = 0; j < 4; ++j)
#pragma unroll
      for (int r = 0; r < 4; ++r) {
        const int row = m0 + wm + i * 16 + quad * 4 + r;
        const int col = n0 + wn + j * 16 + lr;
        const int c = col & 1023;
        float val = (acc[i][j][r] + bias[c]) * qs;
        const int head = c >> 6, hd_i = c & 63;
        const int b_ = row >> 11, pos = row & 2047;
        if (which < 2) {  // RoPE: pair partner is adjacent column = adjacent lane
          const float partner = __shfl_xor(val, 1);
          const float2 cs = tab[(pos << 5) + (hd_i >> 1)];
          val = val * cs.x + partner * ((lane & 1) ? cs.y : -cs.y);
        }
        if (which == 2) {
          vtb[((size_t)((b_ * 16 + head) * 64 + hd_i)) * SEQ + pos] = f2bf(val);
        } else {
          const size_t didx = ((size_t)((b_ * 16 + head) * SEQ + pos)) * 64 + hd_i;
          if (which == 0) qb[didx] = f2bf(val);
          else            kbg[didx] = f2bf(val);
        }
      }
}

// ---------------- O-proj GEMM 128x64 tile, LDS-free, + bias + residual ----------------
__global__ __launch_bounds__(256, 3) void gemm_o_kernel(
    const unsigned short* __restrict__ A,   // 4096 x 1024 bf16 (attn out)
    const unsigned short* __restrict__ Bw,  // 1024 x 1024 bf16 (Wo rows)
    const float* __restrict__ bo, const float* __restrict__ xres, float* __restrict__ out) {
  const int tid = threadIdx.x;
  const int lane = tid & 63, wave = tid >> 6;
  const int lr = lane & 15, quad = lane >> 4;
  const int wm = wave * 32;                       // 4 waves stacked on m
  const int n0 = blockIdx.x * 64, m0 = blockIdx.y * 128;

  const unsigned short* ap[2];
  const unsigned short* bp[4];
#pragma unroll
  for (int i = 0; i < 2; ++i)
    ap[i] = &A[(size_t)(m0 + wm + i * 16 + lr) * 1024 + quad * 8];
#pragma unroll
  for (int j = 0; j < 4; ++j)
    bp[j] = &Bw[(size_t)(n0 + j * 16 + lr) * 1024 + quad * 8];

  f32x4 acc[2][4];
#pragma unroll
  for (int i = 0; i < 2; ++i)
#pragma unroll
    for (int j = 0; j < 4; ++j) acc[i][j] = (f32x4){0.f, 0.f, 0.f, 0.f};

  for (int kt = 0; kt < 16; ++kt) {
#pragma unroll
    for (int kk = 0; kk < 2; ++kk) {
      const int off = kt * 64 + kk * 32;
      short8 a[2], b[4];
#pragma unroll
      for (int i = 0; i < 2; ++i) a[i] = *(const short8*)(ap[i] + off);
#pragma unroll
      for (int j = 0; j < 4; ++j) b[j] = *(const short8*)(bp[j] + off);
#pragma unroll
      for (int i = 0; i < 2; ++i)
#pragma unroll
        for (int j = 0; j < 4; ++j)
          acc[i][j] = __builtin_amdgcn_mfma_f32_16x16x32_bf16(a[i], b[j], acc[i][j], 0, 0, 0);
    }
  }

#pragma unroll
  for (int i = 0; i < 2; ++i)
#pragma unroll
    for (int j = 0; j < 4; ++j)
#pragma unroll
      for (int r = 0; r < 4; ++r) {
        const int row = m0 + wm + i * 16 + quad * 4 + r;
        const int col = n0 + j * 16 + lr;
        const size_t idx = (size_t)row * 1024 + col;
        out[idx] = acc[i][j][r] + bo[col] + xres[idx];
      }
}

// ---------------- attention: LDS-free K/V fragments, per-wave swizzled P ----------------
// 128 q-rows/block (4 waves x 32), 64-key tiles, no barriers in the K-loop.
__global__ __launch_bounds__(256, 2) void attn_kernel(
    const unsigned short* __restrict__ qg, const unsigned short* __restrict__ kg,
    const unsigned short* __restrict__ vtg, unsigned short* __restrict__ ao) {
  __shared__ unsigned short lP[4][32 * 64];  // per-wave P slice, 16B-granule XOR swizzle
  const int tid = threadIdx.x;
  const int lane = tid & 63, w = tid >> 6;
  const int lr = lane & 15, quad = lane >> 4;
  const int r7 = lr & 7;                     // swizzle key (same on write & read)
  const int bh = blockIdx.x >> 4, qt = blockIdx.x & 15;
  const int q0 = qt * 128 + w * 32;
  const unsigned short* Q  = qg + (size_t)bh * SEQ * 64;
  const unsigned short* K  = kg + (size_t)bh * SEQ * 64;
  const unsigned short* VT = vtg + (size_t)bh * 64 * SEQ;
  unsigned short* lPw = lP[w];

  short8 qf[2][2];
#pragma unroll
  for (int t = 0; t < 2; ++t)
#pragma unroll
    for (int kk = 0; kk < 2; ++kk)
      qf[t][kk] = *(const short8*)&Q[(size_t)(q0 + t * 16 + lr) * 64 + kk * 32 + quad * 8];

  short8 onesf;  // B-frag of e0 column: B[0][k]=1 -> row-sum lands in col 0
  {
    const short o1 = (lr == 0) ? (short)0x3F80 : (short)0;
#pragma unroll
    for (int j = 0; j < 8; ++j) onesf[j] = o1;
  }

  f32x4 o[2][4], ol[2];
#pragma unroll
  for (int t = 0; t < 2; ++t) {
    ol[t] = (f32x4){0.f, 0.f, 0.f, 0.f};
#pragma unroll
    for (int d = 0; d < 4; ++d) o[t][d] = (f32x4){0.f, 0.f, 0.f, 0.f};
  }

  // direct-fragment base pointers
  const unsigned short* kp[4];  // A-frag rows: key = kb*16+lr   (advance kt*4096)
  const unsigned short* vp[4];  // B-frag rows: n = d*16+lr      (advance kt*64)
#pragma unroll
  for (int i = 0; i < 4; ++i) {
    kp[i] = &K[(size_t)(i * 16 + lr) * 64 + quad * 8];
    vp[i] = &VT[(size_t)(i * 16 + lr) * SEQ + quad * 8];
  }

  for (int kt = 0; kt < 32; ++kt) {
    // S^T = K . Q^T : C rows = keys (quad*4+r), cols = q (lr). q pre-scaled by 0.125*log2e.
#pragma unroll
    for (int kb = 0; kb < 4; ++kb) {
      const short8 k0 = *(const short8*)(kp[kb] + (size_t)kt * 4096);
      const short8 k1 = *(const short8*)(kp[kb] + (size_t)kt * 4096 + 32);
#pragma unroll
      for (int t = 0; t < 2; ++t) {
        f32x4 st = (f32x4){0.f, 0.f, 0.f, 0.f};
        st = __builtin_amdgcn_mfma_f32_16x16x32_bf16(k0, qf[t][0], st, 0, 0, 0);
        st = __builtin_amdgcn_mfma_f32_16x16x32_bf16(k1, qf[t][1], st, 0, 0, 0);
        // p = 2^st  (no max subtraction: scores are O(1), fp32 range is ample)
        union { float f; unsigned u; } c0, c1, c2, c3;
        c0.f = __builtin_amdgcn_exp2f(st[0]);
        c1.f = __builtin_amdgcn_exp2f(st[1]);
        c2.f = __builtin_amdgcn_exp2f(st[2]);
        c3.f = __builtin_amdgcn_exp2f(st[3]);
        uint2 pw;
        pw.x = __builtin_amdgcn_perm(c1.u, c0.u, 0x07060302u);
        pw.y = __builtin_amdgcn_perm(c3.u, c2.u, 0x07060302u);
        // write P[rr = t*16+lr][16B-group G = kb*2+(quad>>1), half quad&1], G phys = G^r7
        lPw[(t * 16 + lr) * 64 + (((kb * 2 + (quad >> 1)) ^ r7) * 8 + (quad & 1) * 4)] = 0;  // keep addr form
        *(uint2*)&lPw[(t * 16 + lr) * 64 + ((kb * 2 + (quad >> 1)) ^ r7) * 8 + (quad & 1) * 4] = pw;
      }
    }
    __asm__ __volatile__("s_waitcnt lgkmcnt(0)" ::: "memory");

    // PV + row-sum l. pf: A-frag read, 16B-group G = k2*4+quad, phys = G^r7.
#pragma unroll
    for (int k2 = 0; k2 < 2; ++k2) {
      const short8 pf0 = *(const short8*)&lPw[lr * 64 + ((k2 * 4 + quad) ^ r7) * 8];
      const short8 pf1 = *(const short8*)&lPw[(16 + lr) * 64 + ((k2 * 4 + quad) ^ r7) * 8];
      ol[0] = __builtin_amdgcn_mfma_f32_16x16x32_bf16(pf0, onesf, ol[0], 0, 0, 0);
      ol[1] = __builtin_amdgcn_mfma_f32_16x16x32_bf16(pf1, onesf, ol[1], 0, 0, 0);
#pragma unroll
      for (int d = 0; d < 4; ++d) {
        const short8 vf = *(const short8*)(vp[d] + kt * 64 + k2 * 32);
        o[0][d] = __builtin_amdgcn_mfma_f32_16x16x32_bf16(pf0, vf, o[0][d], 0, 0, 0);
        o[1][d] = __builtin_amdgcn_mfma_f32_16x16x32_bf16(pf1, vf, o[1][d], 0, 0, 0);
      }
    }
  }

  const int b_ = bh >> 4, h = bh & 15;
#pragma unroll
  for (int t = 0; t < 2; ++t)
#pragma unroll
    for (int r = 0; r < 4; ++r) {
      const float l = __shfl(ol[t][r], lane & 48);   // broadcast from lr==0 of this quad
      const float rl = 1.0f / l;
#pragma unroll
      for (int d = 0; d < 4; ++d) {
        const int row = q0 + t * 16 + quad * 4 + r;
        ao[(size_t)(b_ * SEQ + row) * 1024 + h * 64 + d * 16 + lr] = f2bf(o[t][d][r] * rl);
      }
    }
}

// ---------------- launch ----------------
extern "C" void kernel_launch(void* const* d_in, const int* in_sizes, int n_in,
                              void* d_out, int out_size, void* d_ws, size_t ws_size,
                              hipStream_t stream) {
  const float* x   = (const float*)d_in[0];
  const float* lnw = (const float*)d_in[1];
  const float* lnb = (const float*)d_in[2];
  const float* Wq  = (const float*)d_in[3];
  const float* bq  = (const float*)d_in[4];
  const float* Wk  = (const float*)d_in[5];
  const float* bk  = (const float*)d_in[6];
  const float* Wv  = (const float*)d_in[7];
  const float* bv  = (const float*)d_in[8];
  const float* Wo  = (const float*)d_in[9];
  const float* bo  = (const float*)d_in[10];
  float* out = (float*)d_out;

  char* ws = (char*)d_ws;
  unsigned short* wqkv = (unsigned short*)(ws);               //  6 MB: [3][1024][1024] bf16
  unsigned short* wob  = (unsigned short*)(ws + 6291456);     //  2 MB
  unsigned short* xn   = (unsigned short*)(ws + 8388608);     //  8 MB: 4096x1024 bf16
  unsigned short* qb   = (unsigned short*)(ws + 16777216);    //  8 MB: (B,H,N,hd)
  unsigned short* kbuf = (unsigned short*)(ws + 25165824);    //  8 MB: (B,H,N,hd)
  unsigned short* vtb  = (unsigned short*)(ws + 33554432);    //  8 MB: (B,H,hd,N)
  unsigned short* ao   = (unsigned short*)(ws + 41943040);    //  8 MB: (B,N,D)
  float2*         tab  = (float2*)(ws + 50331648);            // 512KB

  hipLaunchKernelGGL(prep_kernel, dim3(8448), dim3(256), 0, stream,
                     x, lnw, lnb, Wq, Wk, Wv, Wo, wqkv, wob, xn, tab);
  hipLaunchKernelGGL(gemm_qkv_kernel, dim3(24, 32), dim3(256), 0, stream,
                     xn, wqkv, bq, bk, bv, tab, qb, kbuf, vtb);
  hipLaunchKernelGGL(attn_kernel, dim3(512), dim3(256), 0, stream, qb, kbuf, vtb, ao);
  hipLaunchKernelGGL(gemm_o_kernel, dim3(16, 32), dim3(256), 0, stream,
                     ao, wob, bo, x, out);
}

// Round 8
// 223.178 us; speedup vs baseline: 1.6591x; 1.6591x over previous
//
#include <hip/hip_runtime.h>

// BottleneckAttention: LN -> QKV(+bias) -> RoPE(q,k) -> softmax(QK^T/8)V -> O-proj + residual
// B=2 N=2048 D=1024 H=16 hd=64. bf16 MFMA 16x16x32, fp32 accum.
// Layouts (learn_hip m89/m91): C/D: col=lane&15, row=(lane>>4)*4+reg
//                              A/B: m(or n)=lane&15, k=(lane>>4)*8+j
// v8 = r6 base (best: 222us) + attention reworked:
//   - 128-key tiles: 16 K-loop iters instead of 32 -> half the barrier vmcnt drains;
//     grid 512 @ 2 blocks/CU (64KB LDS) = one full co-resident round, no tail.
//   - lP swizzled (stride 128 shorts, 16B-granule XOR by lr&7) -> kills the 3.1M
//     conflict cycles of the old stride-72 layout.
// (v7 LDS-free direct fragments regressed 2x: 16 cache lines per fragment load.)

#define SEQ 2048
#define LN_EPS 1e-5f

using short8 = __attribute__((ext_vector_type(8))) short;
using f32x4  = __attribute__((ext_vector_type(4))) float;

__device__ __forceinline__ unsigned short f2bf(float f) {
  union { float f; unsigned u; } v; v.f = f;
  unsigned r = v.u + 0x7FFFu + ((v.u >> 16) & 1u);  // RNE
  return (unsigned short)(r >> 16);
}

__device__ __forceinline__ void async16(const void* g, void* l) {
  __builtin_amdgcn_global_load_lds(
      (const __attribute__((address_space(1))) void*)g,
      (__attribute__((address_space(3))) void*)l, 16, 0, 0);
}

// ---------------- fused prep: weight fp32->bf16 | layernorm | rope table ----------------
__global__ __launch_bounds__(256) void prep_kernel(
    const float* __restrict__ x, const float* __restrict__ lnw, const float* __restrict__ lnb,
    const float* __restrict__ wq, const float* __restrict__ wk,
    const float* __restrict__ wv, const float* __restrict__ wo,
    unsigned short* __restrict__ wqkv, unsigned short* __restrict__ wob,
    unsigned short* __restrict__ xn, float2* __restrict__ tab) {
  const int b = blockIdx.x, t = threadIdx.x;
  if (b < 4096) {
    // ---- weight convert: 1M float4 units over 4 matrices ----
    const int gid = b * 256 + t;
    const int m = gid >> 18, e4 = gid & 262143;
    const float* src = (m == 0) ? wq : (m == 1) ? wk : (m == 2) ? wv : wo;
    const float4 v = ((const float4*)src)[e4];
    ushort4 o; o.x = f2bf(v.x); o.y = f2bf(v.y); o.z = f2bf(v.z); o.w = f2bf(v.w);
    if (m < 3) ((ushort4*)wqkv)[(size_t)m * 262144 + e4] = o;
    else       ((ushort4*)wob)[e4] = o;
  } else if (b < 8192) {
    // ---- layernorm row ----
    const int row = b - 4096;
    const float4 v = ((const float4*)(x + (size_t)row * 1024))[t];
    float s  = v.x + v.y + v.z + v.w;
    float s2 = v.x * v.x + v.y * v.y + v.z * v.z + v.w * v.w;
#pragma unroll
    for (int off = 32; off >= 1; off >>= 1) {
      s  += __shfl_xor(s, off);
      s2 += __shfl_xor(s2, off);
    }
    __shared__ float red[8];
    const int lane = t & 63, wave = t >> 6;
    if (lane == 0) { red[wave] = s; red[4 + wave] = s2; }
    __syncthreads();
    s  = red[0] + red[1] + red[2] + red[3];
    s2 = red[4] + red[5] + red[6] + red[7];
    const float mu   = s * (1.0f / 1024.0f);
    const float var  = s2 * (1.0f / 1024.0f) - mu * mu;
    const float rstd = rsqrtf(var + LN_EPS);
    const float4 wv4 = ((const float4*)lnw)[t];
    const float4 bv4 = ((const float4*)lnb)[t];
    ushort4 o;
    o.x = f2bf((v.x - mu) * rstd * wv4.x + bv4.x);
    o.y = f2bf((v.y - mu) * rstd * wv4.y + bv4.y);
    o.z = f2bf((v.z - mu) * rstd * wv4.z + bv4.z);
    o.w = f2bf((v.w - mu) * rstd * wv4.w + bv4.w);
    ((ushort4*)xn)[(size_t)row * 256 + t] = o;
  } else {
    // ---- rope table: tab[pos][i] = (cos, sin), 65536 entries ----
    const int gid = (b - 8192) * 256 + t;
    const int pos = gid >> 5, ip = gid & 31;
    const float invf = exp2f((float)ip * -0.4152410118609203f);  // 10000^(-2i/64)
    const float fr = (float)pos * invf;
    tab[gid] = make_float2(cosf(fr), sinf(fr));
  }
}

// ---------------- 128x128 MFMA GEMM, C = A * Bw^T (+epilogue) ----------------
// LDS swizzle: logical 16B-group g of row r stored at physical g^(r&7).
// mode 0: QKV  -> bias (+0.18*q scale) + RoPE(q,k), write q,k (B,H,N,hd), v^T (B,H,hd,N)
// mode 1: Oproj-> + bo + residual x, fp32 out
__global__ __launch_bounds__(256, 3) void gemm_kernel(
    const unsigned short* __restrict__ A,   // M x 1024 bf16, row-major
    const unsigned short* __restrict__ Bw,  // Ncols x 1024 bf16 (one row per output col)
    int mode,
    const float* __restrict__ bq, const float* __restrict__ bk, const float* __restrict__ bv,
    const float2* __restrict__ tab,
    unsigned short* __restrict__ qb, unsigned short* __restrict__ kbg,
    unsigned short* __restrict__ vtb,
    const float* __restrict__ bo, const float* __restrict__ xres, float* __restrict__ out) {
  __shared__ unsigned short lA[128 * 64];
  __shared__ unsigned short lB[128 * 64];
  const int tid = threadIdx.x;
  const int lane = tid & 63, wave = tid >> 6;
  const int lr = lane & 15, quad = lane >> 4;
  const int wm = (wave >> 1) * 64, wn = (wave & 1) * 64;
  const int n0 = blockIdx.x * 128, m0 = blockIdx.y * 128;
  const int r7 = lr & 7;                                // read-side swizzle key
  const int lrow = lane >> 3, lcg = (lane & 7) ^ lrow;  // write-side: row-in-chunk, swizzled group

  f32x4 acc[4][4];
#pragma unroll
  for (int i = 0; i < 4; ++i)
#pragma unroll
    for (int j = 0; j < 4; ++j) acc[i][j] = (f32x4){0.f, 0.f, 0.f, 0.f};

  for (int kt = 0; kt < 16; ++kt) {
    __syncthreads();
#pragma unroll
    for (int c = 0; c < 4; ++c) {
      const int chunk = wave * 4 + c;               // 0..15: 1KB chunks (8 rows)
      const int grow = chunk * 8 + lrow;
      async16(&A[(size_t)(m0 + grow) * 1024 + kt * 64 + lcg * 8], &lA[chunk * 512]);
      async16(&Bw[(size_t)(n0 + grow) * 1024 + kt * 64 + lcg * 8], &lB[chunk * 512]);
    }
    __syncthreads();
#pragma unroll
    for (int kk = 0; kk < 2; ++kk) {
      short8 a[4], b[4];
#pragma unroll
      for (int i = 0; i < 4; ++i)
        a[i] = *(const short8*)&lA[(wm + i * 16 + lr) * 64 + ((kk * 4 + quad) ^ r7) * 8];
#pragma unroll
      for (int j = 0; j < 4; ++j)
        b[j] = *(const short8*)&lB[(wn + j * 16 + lr) * 64 + ((kk * 4 + quad) ^ r7) * 8];
#pragma unroll
      for (int i = 0; i < 4; ++i)
#pragma unroll
        for (int j = 0; j < 4; ++j)
          acc[i][j] = __builtin_amdgcn_mfma_f32_16x16x32_bf16(a[i], b[j], acc[i][j], 0, 0, 0);
    }
  }

  if (mode == 0) {
    const int which = n0 >> 10;  // block-uniform: 0=q 1=k 2=v
    const float* bias = (which == 0) ? bq : (which == 1) ? bk : bv;
    const float qs = (which == 0) ? 0.18033688011112042f : 1.0f;  // 0.125*log2(e)
#pragma unroll
    for (int i = 0; i < 4; ++i)
#pragma unroll
      for (int j = 0; j < 4; ++j)
#pragma unroll
        for (int r = 0; r < 4; ++r) {
          const int row = m0 + wm + i * 16 + quad * 4 + r;
          const int col = n0 + wn + j * 16 + lr;
          const int c = col & 1023;
          float val = (acc[i][j][r] + bias[c]) * qs;
          const int head = c >> 6, hd_i = c & 63;
          const int b_ = row >> 11, pos = row & 2047;
          if (which < 2) {  // RoPE: pair partner is adjacent column = adjacent lane
            const float partner = __shfl_xor(val, 1);
            const float2 cs = tab[(pos << 5) + (hd_i >> 1)];
            val = val * cs.x + partner * ((lane & 1) ? cs.y : -cs.y);
          }
          if (which == 2) {
            vtb[((size_t)((b_ * 16 + head) * 64 + hd_i)) * SEQ + pos] = f2bf(val);
          } else {
            const size_t didx = ((size_t)((b_ * 16 + head) * SEQ + pos)) * 64 + hd_i;
            if (which == 0) qb[didx] = f2bf(val);
            else            kbg[didx] = f2bf(val);
          }
        }
  } else {
#pragma unroll
    for (int i = 0; i < 4; ++i)
#pragma unroll
      for (int j = 0; j < 4; ++j)
#pragma unroll
        for (int r = 0; r < 4; ++r) {
          const int row = m0 + wm + i * 16 + quad * 4 + r;
          const int col = n0 + wn + j * 16 + lr;
          const size_t idx = (size_t)row * 1024 + col;
          out[idx] = acc[i][j][r] + bo[col] + xres[idx];
        }
  }
}

// ---------------- attention v8: 128 q-rows/block, 128-KEY tiles, 16 iters ----------------
// lK 128x64 swizzled, lV (V^T) 64x128 swizzled, lP 128x128 swizzled per-wave slices.
__global__ __launch_bounds__(256) void attn_kernel(
    const unsigned short* __restrict__ qg, const unsigned short* __restrict__ kg,
    const unsigned short* __restrict__ vtg, unsigned short* __restrict__ ao) {
  __shared__ unsigned short lK[128 * 64];    // 128 keys x 64 d   (16 KB)
  __shared__ unsigned short lV[64 * 128];    // V^T: 64 d x 128 k (16 KB)
  __shared__ unsigned short lP[4][32 * 128]; // per-wave P slice  (32 KB)
  const int tid = threadIdx.x;
  const int lane = tid & 63, w = tid >> 6;
  const int lr = lane & 15, quad = lane >> 4;
  const int r7 = lr & 7;
  const int bh = blockIdx.x >> 4, qt = blockIdx.x & 15;
  const int q0 = qt * 128 + w * 32;
  const unsigned short* Q  = qg + (size_t)bh * SEQ * 64;
  const unsigned short* K  = kg + (size_t)bh * SEQ * 64;
  const unsigned short* VT = vtg + (size_t)bh * 64 * SEQ;
  unsigned short* lPw = lP[w];

  short8 qf[2][2];
#pragma unroll
  for (int t = 0; t < 2; ++t)
#pragma unroll
    for (int kk = 0; kk < 2; ++kk)
      qf[t][kk] = *(const short8*)&Q[(size_t)(q0 + t * 16 + lr) * 64 + kk * 32 + quad * 8];

  short8 onesf;  // B-frag of e0 column: B[0][k]=1 -> row-sum lands in col 0
  {
    const short o1 = (lr == 0) ? (short)0x3F80 : (short)0;
#pragma unroll
    for (int j = 0; j < 8; ++j) onesf[j] = o1;
  }

  f32x4 o[2][4], ol[2];
#pragma unroll
  for (int t = 0; t < 2; ++t) {
    ol[t] = (f32x4){0.f, 0.f, 0.f, 0.f};
#pragma unroll
    for (int d = 0; d < 4; ++d) o[t][d] = (f32x4){0.f, 0.f, 0.f, 0.f};
  }

  // staging lane decomposition
  const int k_row = lane >> 3, k_g = (lane & 7) ^ (k_row & 7);   // lK: 8 rows x 8 granules/chunk
  const int v_row = lane >> 4, v_g0 = lane & 15;                  // lV: 4 rows x 16 granules/chunk

  for (int kt = 0; kt < 16; ++kt) {
    __syncthreads();
#pragma unroll
    for (int c = 0; c < 4; ++c) {
      const int kc = w * 4 + c;                         // 16 chunks of lK (8 rows each)
      const int krow = kc * 8 + k_row;
      async16(&K[(size_t)(kt * 128 + krow) * 64 + k_g * 8], &lK[kc * 512]);
      const int vc = w * 4 + c;                         // 16 chunks of lV (4 rows each)
      const int vrow = vc * 4 + v_row;
      const int vg = v_g0 ^ (vrow & 7);
      async16(&VT[(size_t)vrow * SEQ + kt * 128 + vg * 8], &lV[vc * 512]);
    }
    __syncthreads();

    // S^T = K . Q^T : C rows = keys (quad*4+r), cols = q (lr). q pre-scaled by 0.125*log2e.
#pragma unroll
    for (int kb = 0; kb < 8; ++kb) {
      const short8 k0 = *(const short8*)&lK[(kb * 16 + lr) * 64 + (quad ^ r7) * 8];
      const short8 k1 = *(const short8*)&lK[(kb * 16 + lr) * 64 + ((4 + quad) ^ r7) * 8];
#pragma unroll
      for (int t = 0; t < 2; ++t) {
        f32x4 st = (f32x4){0.f, 0.f, 0.f, 0.f};
        st = __builtin_amdgcn_mfma_f32_16x16x32_bf16(k0, qf[t][0], st, 0, 0, 0);
        st = __builtin_amdgcn_mfma_f32_16x16x32_bf16(k1, qf[t][1], st, 0, 0, 0);
        // p = 2^st  (no max subtraction: scores are O(1), fp32 range is ample)
        union { float f; unsigned u; } c0, c1, c2, c3;
        c0.f = __builtin_amdgcn_exp2f(st[0]);
        c1.f = __builtin_amdgcn_exp2f(st[1]);
        c2.f = __builtin_amdgcn_exp2f(st[2]);
        c3.f = __builtin_amdgcn_exp2f(st[3]);
        uint2 pw;
        pw.x = __builtin_amdgcn_perm(c1.u, c0.u, 0x07060302u);
        pw.y = __builtin_amdgcn_perm(c3.u, c2.u, 0x07060302u);
        // P[q=t*16+lr][keys kb*16+quad*4..+3]; granule G=kb*2+(quad>>1), phys G^r7
        *(uint2*)&lPw[(t * 16 + lr) * 128 + ((kb * 2 + (quad >> 1)) ^ r7) * 8 + (quad & 1) * 4] = pw;
      }
    }
    __asm__ __volatile__("s_waitcnt lgkmcnt(0)" ::: "memory");

    // PV + row-sum l. pf: A-frag of P, granule G = k2*4+quad, phys G^r7.
#pragma unroll
    for (int k2 = 0; k2 < 4; ++k2) {
      const short8 pf0 = *(const short8*)&lPw[lr * 128 + ((k2 * 4 + quad) ^ r7) * 8];
      const short8 pf1 = *(const short8*)&lPw[(16 + lr) * 128 + ((k2 * 4 + quad) ^ r7) * 8];
      ol[0] = __builtin_amdgcn_mfma_f32_16x16x32_bf16(pf0, onesf, ol[0], 0, 0, 0);
      ol[1] = __builtin_amdgcn_mfma_f32_16x16x32_bf16(pf1, onesf, ol[1], 0, 0, 0);
#pragma unroll
      for (int d = 0; d < 4; ++d) {
        const short8 vf = *(const short8*)&lV[(d * 16 + lr) * 128 + ((k2 * 4 + quad) ^ r7) * 8];
        o[0][d] = __builtin_amdgcn_mfma_f32_16x16x32_bf16(pf0, vf, o[0][d], 0, 0, 0);
        o[1][d] = __builtin_amdgcn_mfma_f32_16x16x32_bf16(pf1, vf, o[1][d], 0, 0, 0);
      }
    }
  }

  const int b_ = bh >> 4, h = bh & 15;
#pragma unroll
  for (int t = 0; t < 2; ++t)
#pragma unroll
    for (int r = 0; r < 4; ++r) {
      const float l = __shfl(ol[t][r], lane & 48);   // broadcast from lr==0 of this quad
      const float rl = 1.0f / l;
#pragma unroll
      for (int d = 0; d < 4; ++d) {
        const int row = q0 + t * 16 + quad * 4 + r;
        ao[(size_t)(b_ * SEQ + row) * 1024 + h * 64 + d * 16 + lr] = f2bf(o[t][d][r] * rl);
      }
    }
}

// ---------------- launch ----------------
extern "C" void kernel_launch(void* const* d_in, const int* in_sizes, int n_in,
                              void* d_out, int out_size, void* d_ws, size_t ws_size,
                              hipStream_t stream) {
  const float* x   = (const float*)d_in[0];
  const float* lnw = (const float*)d_in[1];
  const float* lnb = (const float*)d_in[2];
  const float* Wq  = (const float*)d_in[3];
  const float* bq  = (const float*)d_in[4];
  const float* Wk  = (const float*)d_in[5];
  const float* bk  = (const float*)d_in[6];
  const float* Wv  = (const float*)d_in[7];
  const float* bv  = (const float*)d_in[8];
  const float* Wo  = (const float*)d_in[9];
  const float* bo  = (const float*)d_in[10];
  float* out = (float*)d_out;

  char* ws = (char*)d_ws;
  unsigned short* wqkv = (unsigned short*)(ws);               //  6 MB: [3][1024][1024] bf16
  unsigned short* wob  = (unsigned short*)(ws + 6291456);     //  2 MB
  unsigned short* xn   = (unsigned short*)(ws + 8388608);     //  8 MB: 4096x1024 bf16
  unsigned short* qb   = (unsigned short*)(ws + 16777216);    //  8 MB: (B,H,N,hd)
  unsigned short* kbuf = (unsigned short*)(ws + 25165824);    //  8 MB: (B,H,N,hd)
  unsigned short* vtb  = (unsigned short*)(ws + 33554432);    //  8 MB: (B,H,hd,N)
  unsigned short* ao   = (unsigned short*)(ws + 41943040);    //  8 MB: (B,N,D)
  float2*         tab  = (float2*)(ws + 50331648);            // 512KB

  hipLaunchKernelGGL(prep_kernel, dim3(8448), dim3(256), 0, stream,
                     x, lnw, lnb, Wq, Wk, Wv, Wo, wqkv, wob, xn, tab);
  hipLaunchKernelGGL(gemm_kernel, dim3(24, 32), dim3(256), 0, stream,
                     xn, wqkv, 0, bq, bk, bv, tab, qb, kbuf, vtb,
                     (const float*)nullptr, (const float*)nullptr, (float*)nullptr);
  hipLaunchKernelGGL(attn_kernel, dim3(512), dim3(256), 0, stream, qb, kbuf, vtb, ao);
  hipLaunchKernelGGL(gemm_kernel, dim3(8, 32), dim3(256), 0, stream,
                     ao, wob, 1,
                     (const float*)nullptr, (const float*)nullptr, (const float*)nullptr, tab,
                     (unsigned short*)nullptr, (unsigned short*)nullptr, (unsigned short*)nullptr,
                     bo, x, out);
}

// Round 9
// 211.427 us; speedup vs baseline: 1.7514x; 1.0556x over previous
//
#include <hip/hip_runtime.h>

// BottleneckAttention: LN -> QKV(+bias) -> RoPE(q,k) -> softmax(QK^T/8)V -> O-proj + residual
// B=2 N=2048 D=1024 H=16 hd=64. bf16 MFMA 16x16x32, fp32 accum.
// Layouts (learn_hip m89/m91): C/D: col=lane&15, row=(lane>>4)*4+reg
//                              A/B: m(or n)=lane&15, k=(lane>>4)*8+j
// v9 = r8 + K-loop PHASE STAGGER: co-resident blocks (linear id +-256) start
// the K-loop at rotated kt (gemm 0/5/10, attn 0/8) so one block's VMEM stage
// overlaps another's LDS+MFMA compute (breaks the barrier convoy; summation
// order is commutative — attention has no online max, pure sums).
// O-proj gets a staged 128x64-tile kernel: 512 blocks -> 2/CU co-res + stagger.

#define SEQ 2048
#define LN_EPS 1e-5f

using short8 = __attribute__((ext_vector_type(8))) short;
using f32x4  = __attribute__((ext_vector_type(4))) float;

__device__ __forceinline__ unsigned short f2bf(float f) {
  union { float f; unsigned u; } v; v.f = f;
  unsigned r = v.u + 0x7FFFu + ((v.u >> 16) & 1u);  // RNE
  return (unsigned short)(r >> 16);
}

__device__ __forceinline__ void async16(const void* g, void* l) {
  __builtin_amdgcn_global_load_lds(
      (const __attribute__((address_space(1))) void*)g,
      (__attribute__((address_space(3))) void*)l, 16, 0, 0);
}

// ---------------- fused prep: weight fp32->bf16 | layernorm | rope table ----------------
__global__ __launch_bounds__(256) void prep_kernel(
    const float* __restrict__ x, const float* __restrict__ lnw, const float* __restrict__ lnb,
    const float* __restrict__ wq, const float* __restrict__ wk,
    const float* __restrict__ wv, const float* __restrict__ wo,
    unsigned short* __restrict__ wqkv, unsigned short* __restrict__ wob,
    unsigned short* __restrict__ xn, float2* __restrict__ tab) {
  const int b = blockIdx.x, t = threadIdx.x;
  if (b < 4096) {
    // ---- weight convert: 1M float4 units over 4 matrices ----
    const int gid = b * 256 + t;
    const int m = gid >> 18, e4 = gid & 262143;
    const float* src = (m == 0) ? wq : (m == 1) ? wk : (m == 2) ? wv : wo;
    const float4 v = ((const float4*)src)[e4];
    ushort4 o; o.x = f2bf(v.x); o.y = f2bf(v.y); o.z = f2bf(v.z); o.w = f2bf(v.w);
    if (m < 3) ((ushort4*)wqkv)[(size_t)m * 262144 + e4] = o;
    else       ((ushort4*)wob)[e4] = o;
  } else if (b < 8192) {
    // ---- layernorm row ----
    const int row = b - 4096;
    const float4 v = ((const float4*)(x + (size_t)row * 1024))[t];
    float s  = v.x + v.y + v.z + v.w;
    float s2 = v.x * v.x + v.y * v.y + v.z * v.z + v.w * v.w;
#pragma unroll
    for (int off = 32; off >= 1; off >>= 1) {
      s  += __shfl_xor(s, off);
      s2 += __shfl_xor(s2, off);
    }
    __shared__ float red[8];
    const int lane = t & 63, wave = t >> 6;
    if (lane == 0) { red[wave] = s; red[4 + wave] = s2; }
    __syncthreads();
    s  = red[0] + red[1] + red[2] + red[3];
    s2 = red[4] + red[5] + red[6] + red[7];
    const float mu   = s * (1.0f / 1024.0f);
    const float var  = s2 * (1.0f / 1024.0f) - mu * mu;
    const float rstd = rsqrtf(var + LN_EPS);
    const float4 wv4 = ((const float4*)lnw)[t];
    const float4 bv4 = ((const float4*)lnb)[t];
    ushort4 o;
    o.x = f2bf((v.x - mu) * rstd * wv4.x + bv4.x);
    o.y = f2bf((v.y - mu) * rstd * wv4.y + bv4.y);
    o.z = f2bf((v.z - mu) * rstd * wv4.z + bv4.z);
    o.w = f2bf((v.w - mu) * rstd * wv4.w + bv4.w);
    ((ushort4*)xn)[(size_t)row * 256 + t] = o;
  } else {
    // ---- rope table: tab[pos][i] = (cos, sin), 65536 entries ----
    const int gid = (b - 8192) * 256 + t;
    const int pos = gid >> 5, ip = gid & 31;
    const float invf = exp2f((float)ip * -0.4152410118609203f);  // 10000^(-2i/64)
    const float fr = (float)pos * invf;
    tab[gid] = make_float2(cosf(fr), sinf(fr));
  }
}

// ---------------- QKV GEMM 128x128, staged + swizzled + phase-staggered ----------------
__global__ __launch_bounds__(256, 3) void gemm_qkv_kernel(
    const unsigned short* __restrict__ A,   // 4096 x 1024 bf16 (xn)
    const unsigned short* __restrict__ Bw,  // 3072 x 1024 bf16 (Wq;Wk;Wv rows)
    const float* __restrict__ bq, const float* __restrict__ bk, const float* __restrict__ bv,
    const float2* __restrict__ tab,
    unsigned short* __restrict__ qb, unsigned short* __restrict__ kbg,
    unsigned short* __restrict__ vtb) {
  __shared__ unsigned short lA[128 * 64];
  __shared__ unsigned short lB[128 * 64];
  const int tid = threadIdx.x;
  const int lane = tid & 63, wave = tid >> 6;
  const int lr = lane & 15, quad = lane >> 4;
  const int wm = (wave >> 1) * 64, wn = (wave & 1) * 64;
  const int n0 = blockIdx.x * 128, m0 = blockIdx.y * 128;
  const int r7 = lr & 7;                                // read-side swizzle key
  const int lrow = lane >> 3, lcg = (lane & 7) ^ lrow;  // write-side: row-in-chunk, swizzled group
  const int lin = blockIdx.y * gridDim.x + blockIdx.x;
  const int phase = ((lin >> 8) * 5) & 15;              // co-res rounds get 0/5/10

  f32x4 acc[4][4];
#pragma unroll
  for (int i = 0; i < 4; ++i)
#pragma unroll
    for (int j = 0; j < 4; ++j) acc[i][j] = (f32x4){0.f, 0.f, 0.f, 0.f};

  for (int kt = 0; kt < 16; ++kt) {
    const int kofs = ((kt + phase) & 15) * 64;
    __syncthreads();
#pragma unroll
    for (int c = 0; c < 4; ++c) {
      const int chunk = wave * 4 + c;               // 0..15: 1KB chunks (8 rows)
      const int grow = chunk * 8 + lrow;
      async16(&A[(size_t)(m0 + grow) * 1024 + kofs + lcg * 8], &lA[chunk * 512]);
      async16(&Bw[(size_t)(n0 + grow) * 1024 + kofs + lcg * 8], &lB[chunk * 512]);
    }
    __syncthreads();
#pragma unroll
    for (int kk = 0; kk < 2; ++kk) {
      short8 a[4], b[4];
#pragma unroll
      for (int i = 0; i < 4; ++i)
        a[i] = *(const short8*)&lA[(wm + i * 16 + lr) * 64 + ((kk * 4 + quad) ^ r7) * 8];
#pragma unroll
      for (int j = 0; j < 4; ++j)
        b[j] = *(const short8*)&lB[(wn + j * 16 + lr) * 64 + ((kk * 4 + quad) ^ r7) * 8];
#pragma unroll
      for (int i = 0; i < 4; ++i)
#pragma unroll
        for (int j = 0; j < 4; ++j)
          acc[i][j] = __builtin_amdgcn_mfma_f32_16x16x32_bf16(a[i], b[j], acc[i][j], 0, 0, 0);
    }
  }

  const int which = n0 >> 10;  // block-uniform: 0=q 1=k 2=v
  const float* bias = (which == 0) ? bq : (which == 1) ? bk : bv;
  const float qs = (which == 0) ? 0.18033688011112042f : 1.0f;  // 0.125*log2(e)
#pragma unroll
  for (int i = 0; i < 4; ++i)
#pragma unroll
    for (int j = 0; j < 4; ++j)
#pragma unroll
      for (int r = 0; r < 4; ++r) {
        const int row = m0 + wm + i * 16 + quad * 4 + r;
        const int col = n0 + wn + j * 16 + lr;
        const int c = col & 1023;
        float val = (acc[i][j][r] + bias[c]) * qs;
        const int head = c >> 6, hd_i = c & 63;
        const int b_ = row >> 11, pos = row & 2047;
        if (which < 2) {  // RoPE: pair partner is adjacent column = adjacent lane
          const float partner = __shfl_xor(val, 1);
          const float2 cs = tab[(pos << 5) + (hd_i >> 1)];
          val = val * cs.x + partner * ((lane & 1) ? cs.y : -cs.y);
        }
        if (which == 2) {
          vtb[((size_t)((b_ * 16 + head) * 64 + hd_i)) * SEQ + pos] = f2bf(val);
        } else {
          const size_t didx = ((size_t)((b_ * 16 + head) * SEQ + pos)) * 64 + hd_i;
          if (which == 0) qb[didx] = f2bf(val);
          else            kbg[didx] = f2bf(val);
        }
      }
}

// ---------------- O-proj GEMM 128x64 tile, staged + swizzled + staggered ----------------
__global__ __launch_bounds__(256, 3) void gemm_o_kernel(
    const unsigned short* __restrict__ A,   // 4096 x 1024 bf16 (attn out)
    const unsigned short* __restrict__ Bw,  // 1024 x 1024 bf16 (Wo rows)
    const float* __restrict__ bo, const float* __restrict__ xres, float* __restrict__ out) {
  __shared__ unsigned short lA[128 * 64];   // 16 KB
  __shared__ unsigned short lB[64 * 64];    //  8 KB
  const int tid = threadIdx.x;
  const int lane = tid & 63, wave = tid >> 6;
  const int lr = lane & 15, quad = lane >> 4;
  const int wm = (wave >> 1) * 64, wn = (wave & 1) * 32;
  const int n0 = blockIdx.x * 64, m0 = blockIdx.y * 128;
  const int r7 = lr & 7;
  const int lrow = lane >> 3, lcg = (lane & 7) ^ lrow;
  const int lin = blockIdx.y * gridDim.x + blockIdx.x;
  const int phase = ((lin >> 8) * 8) & 15;              // co-res rounds get 0/8

  f32x4 acc[4][2];
#pragma unroll
  for (int i = 0; i < 4; ++i)
#pragma unroll
    for (int j = 0; j < 2; ++j) acc[i][j] = (f32x4){0.f, 0.f, 0.f, 0.f};

  for (int kt = 0; kt < 16; ++kt) {
    const int kofs = ((kt + phase) & 15) * 64;
    __syncthreads();
#pragma unroll
    for (int c = 0; c < 4; ++c) {
      const int chunk = wave * 4 + c;               // lA: 16 chunks (8 rows each)
      const int grow = chunk * 8 + lrow;
      async16(&A[(size_t)(m0 + grow) * 1024 + kofs + lcg * 8], &lA[chunk * 512]);
    }
#pragma unroll
    for (int c = 0; c < 2; ++c) {
      const int chunk = wave * 2 + c;               // lB: 8 chunks (8 rows each)
      const int grow = chunk * 8 + lrow;
      async16(&Bw[(size_t)(n0 + grow) * 1024 + kofs + lcg * 8], &lB[chunk * 512]);
    }
    __syncthreads();
#pragma unroll
    for (int kk = 0; kk < 2; ++kk) {
      short8 a[4], b[2];
#pragma unroll
      for (int i = 0; i < 4; ++i)
        a[i] = *(const short8*)&lA[(wm + i * 16 + lr) * 64 + ((kk * 4 + quad) ^ r7) * 8];
#pragma unroll
      for (int j = 0; j < 2; ++j)
        b[j] = *(const short8*)&lB[(wn + j * 16 + lr) * 64 + ((kk * 4 + quad) ^ r7) * 8];
#pragma unroll
      for (int i = 0; i < 4; ++i)
#pragma unroll
        for (int j = 0; j < 2; ++j)
          acc[i][j] = __builtin_amdgcn_mfma_f32_16x16x32_bf16(a[i], b[j], acc[i][j], 0, 0, 0);
    }
  }

#pragma unroll
  for (int i = 0; i < 4; ++i)
#pragma unroll
    for (int j = 0; j < 2; ++j)
#pragma unroll
      for (int r = 0; r < 4; ++r) {
        const int row = m0 + wm + i * 16 + quad * 4 + r;
        const int col = n0 + wn + j * 16 + lr;
        const size_t idx = (size_t)row * 1024 + col;
        out[idx] = acc[i][j][r] + bo[col] + xres[idx];
      }
}

// ---------------- attention: 128 q-rows/block, 128-key tiles, phase-staggered ----------------
__global__ __launch_bounds__(256) void attn_kernel(
    const unsigned short* __restrict__ qg, const unsigned short* __restrict__ kg,
    const unsigned short* __restrict__ vtg, unsigned short* __restrict__ ao) {
  __shared__ unsigned short lK[128 * 64];    // 128 keys x 64 d   (16 KB)
  __shared__ unsigned short lV[64 * 128];    // V^T: 64 d x 128 k (16 KB)
  __shared__ unsigned short lP[4][32 * 128]; // per-wave P slice  (32 KB)
  const int tid = threadIdx.x;
  const int lane = tid & 63, w = tid >> 6;
  const int lr = lane & 15, quad = lane >> 4;
  const int r7 = lr & 7;
  const int bh = blockIdx.x >> 4, qt = blockIdx.x & 15;
  const int q0 = qt * 128 + w * 32;
  const int phase = ((blockIdx.x >> 8) * 8) & 15;       // co-res rounds get 0/8
  const unsigned short* Q  = qg + (size_t)bh * SEQ * 64;
  const unsigned short* K  = kg + (size_t)bh * SEQ * 64;
  const unsigned short* VT = vtg + (size_t)bh * 64 * SEQ;
  unsigned short* lPw = lP[w];

  short8 qf[2][2];
#pragma unroll
  for (int t = 0; t < 2; ++t)
#pragma unroll
    for (int kk = 0; kk < 2; ++kk)
      qf[t][kk] = *(const short8*)&Q[(size_t)(q0 + t * 16 + lr) * 64 + kk * 32 + quad * 8];

  short8 onesf;  // B-frag of e0 column: B[0][k]=1 -> row-sum lands in col 0
  {
    const short o1 = (lr == 0) ? (short)0x3F80 : (short)0;
#pragma unroll
    for (int j = 0; j < 8; ++j) onesf[j] = o1;
  }

  f32x4 o[2][4], ol[2];
#pragma unroll
  for (int t = 0; t < 2; ++t) {
    ol[t] = (f32x4){0.f, 0.f, 0.f, 0.f};
#pragma unroll
    for (int d = 0; d < 4; ++d) o[t][d] = (f32x4){0.f, 0.f, 0.f, 0.f};
  }

  // staging lane decomposition
  const int k_row = lane >> 3, k_g = (lane & 7) ^ (k_row & 7);   // lK: 8 rows x 8 granules/chunk
  const int v_row = lane >> 4, v_g0 = lane & 15;                  // lV: 4 rows x 16 granules/chunk

  for (int kt = 0; kt < 16; ++kt) {
    const int kb0 = ((kt + phase) & 15) * 128;   // rotated key-tile base (sums are commutative)
    __syncthreads();
#pragma unroll
    for (int c = 0; c < 4; ++c) {
      const int kc = w * 4 + c;                         // 16 chunks of lK (8 rows each)
      const int krow = kc * 8 + k_row;
      async16(&K[(size_t)(kb0 + krow) * 64 + k_g * 8], &lK[kc * 512]);
      const int vc = w * 4 + c;                         // 16 chunks of lV (4 rows each)
      const int vrow = vc * 4 + v_row;
      const int vg = v_g0 ^ (vrow & 7);
      async16(&VT[(size_t)vrow * SEQ + kb0 + vg * 8], &lV[vc * 512]);
    }
    __syncthreads();

    // S^T = K . Q^T : C rows = keys (quad*4+r), cols = q (lr). q pre-scaled by 0.125*log2e.
#pragma unroll
    for (int kb = 0; kb < 8; ++kb) {
      const short8 k0 = *(const short8*)&lK[(kb * 16 + lr) * 64 + (quad ^ r7) * 8];
      const short8 k1 = *(const short8*)&lK[(kb * 16 + lr) * 64 + ((4 + quad) ^ r7) * 8];
#pragma unroll
      for (int t = 0; t < 2; ++t) {
        f32x4 st = (f32x4){0.f, 0.f, 0.f, 0.f};
        st = __builtin_amdgcn_mfma_f32_16x16x32_bf16(k0, qf[t][0], st, 0, 0, 0);
        st = __builtin_amdgcn_mfma_f32_16x16x32_bf16(k1, qf[t][1], st, 0, 0, 0);
        // p = 2^st  (no max subtraction: scores are O(1), fp32 range is ample)
        union { float f; unsigned u; } c0, c1, c2, c3;
        c0.f = __builtin_amdgcn_exp2f(st[0]);
        c1.f = __builtin_amdgcn_exp2f(st[1]);
        c2.f = __builtin_amdgcn_exp2f(st[2]);
        c3.f = __builtin_amdgcn_exp2f(st[3]);
        uint2 pw;
        pw.x = __builtin_amdgcn_perm(c1.u, c0.u, 0x07060302u);
        pw.y = __builtin_amdgcn_perm(c3.u, c2.u, 0x07060302u);
        // P[q=t*16+lr][keys kb*16+quad*4..+3]; granule G=kb*2+(quad>>1), phys G^r7
        *(uint2*)&lPw[(t * 16 + lr) * 128 + ((kb * 2 + (quad >> 1)) ^ r7) * 8 + (quad & 1) * 4] = pw;
      }
    }
    __asm__ __volatile__("s_waitcnt lgkmcnt(0)" ::: "memory");

    // PV + row-sum l. pf: A-frag of P, granule G = k2*4+quad, phys G^r7.
#pragma unroll
    for (int k2 = 0; k2 < 4; ++k2) {
      const short8 pf0 = *(const short8*)&lPw[lr * 128 + ((k2 * 4 + quad) ^ r7) * 8];
      const short8 pf1 = *(const short8*)&lPw[(16 + lr) * 128 + ((k2 * 4 + quad) ^ r7) * 8];
      ol[0] = __builtin_amdgcn_mfma_f32_16x16x32_bf16(pf0, onesf, ol[0], 0, 0, 0);
      ol[1] = __builtin_amdgcn_mfma_f32_16x16x32_bf16(pf1, onesf, ol[1], 0, 0, 0);
#pragma unroll
      for (int d = 0; d < 4; ++d) {
        const short8 vf = *(const short8*)&lV[(d * 16 + lr) * 128 + ((k2 * 4 + quad) ^ r7) * 8];
        o[0][d] = __builtin_amdgcn_mfma_f32_16x16x32_bf16(pf0, vf, o[0][d], 0, 0, 0);
        o[1][d] = __builtin_amdgcn_mfma_f32_16x16x32_bf16(pf1, vf, o[1][d], 0, 0, 0);
      }
    }
  }

  const int b_ = bh >> 4, h = bh & 15;
#pragma unroll
  for (int t = 0; t < 2; ++t)
#pragma unroll
    for (int r = 0; r < 4; ++r) {
      const float l = __shfl(ol[t][r], lane & 48);   // broadcast from lr==0 of this quad
      const float rl = 1.0f / l;
#pragma unroll
      for (int d = 0; d < 4; ++d) {
        const int row = q0 + t * 16 + quad * 4 + r;
        ao[(size_t)(b_ * SEQ + row) * 1024 + h * 64 + d * 16 + lr] = f2bf(o[t][d][r] * rl);
      }
    }
}

// ---------------- launch ----------------
extern "C" void kernel_launch(void* const* d_in, const int* in_sizes, int n_in,
                              void* d_out, int out_size, void* d_ws, size_t ws_size,
                              hipStream_t stream) {
  const float* x   = (const float*)d_in[0];
  const float* lnw = (const float*)d_in[1];
  const float* lnb = (const float*)d_in[2];
  const float* Wq  = (const float*)d_in[3];
  const float* bq  = (const float*)d_in[4];
  const float* Wk  = (const float*)d_in[5];
  const float* bk  = (const float*)d_in[6];
  const float* Wv  = (const float*)d_in[7];
  const float* bv  = (const float*)d_in[8];
  const float* Wo  = (const float*)d_in[9];
  const float* bo  = (const float*)d_in[10];
  float* out = (float*)d_out;

  char* ws = (char*)d_ws;
  unsigned short* wqkv = (unsigned short*)(ws);               //  6 MB: [3][1024][1024] bf16
  unsigned short* wob  = (unsigned short*)(ws + 6291456);     //  2 MB
  unsigned short* xn   = (unsigned short*)(ws + 8388608);     //  8 MB: 4096x1024 bf16
  unsigned short* qb   = (unsigned short*)(ws + 16777216);    //  8 MB: (B,H,N,hd)
  unsigned short* kbuf = (unsigned short*)(ws + 25165824);    //  8 MB: (B,H,N,hd)
  unsigned short* vtb  = (unsigned short*)(ws + 33554432);    //  8 MB: (B,H,hd,N)
  unsigned short* ao   = (unsigned short*)(ws + 41943040);    //  8 MB: (B,N,D)
  float2*         tab  = (float2*)(ws + 50331648);            // 512KB

  hipLaunchKernelGGL(prep_kernel, dim3(8448), dim3(256), 0, stream,
                     x, lnw, lnb, Wq, Wk, Wv, Wo, wqkv, wob, xn, tab);
  hipLaunchKernelGGL(gemm_qkv_kernel, dim3(24, 32), dim3(256), 0, stream,
                     xn, wqkv, bq, bk, bv, tab, qb, kbuf, vtb);
  hipLaunchKernelGGL(attn_kernel, dim3(512), dim3(256), 0, stream, qb, kbuf, vtb, ao);
  hipLaunchKernelGGL(gemm_o_kernel, dim3(16, 32), dim3(256), 0, stream,
                     ao, wob, bo, x, out);
}